// Round 6
// baseline (339.212 us; speedup 1.0000x reference)
//
#include <hip/hip_runtime.h>

typedef float v2f __attribute__((ext_vector_type(2)));
typedef float v4f __attribute__((ext_vector_type(4)));

#define KH 5
#define KW 5
#define HH 256
#define WW 256
#define HO 252
#define WO 252
#define NB 16
#define NO 64
#define PLANE (HO * WO)

// ---- workspace layout (d_ws): cinv[63616] then pn[16*63504 + 64] ----
#define CINV_FLOATS 63616            // 252*252 rounded up + slack for x4 overreads
#define PN_FLOATS   (NB * PLANE + 64)

// ================= pass 1: per-pixel stats -> cinv, pn =================
// (byte-identical to round 5 — control variable)
#define T1W 64
#define XC1 69                        // 68 cols + 1 pad

__global__ __launch_bounds__(512, 4)
void rbf_stats_kernel(const float* __restrict__ x, const float* __restrict__ w,
                      float* __restrict__ cinvb, float* __restrict__ pnb) {
    __shared__ float xs[NB][KH][XC1];
    __shared__ float wn[NO];
    __shared__ float pS1[8][T1W];
    __shared__ float pS2[8][T1W];

    const int t  = threadIdx.x;
    const int k  = blockIdx.y;
    const int l0 = (int)blockIdx.x * T1W;

    for (int idx = t; idx < NB * KH * 68; idx += 512) {
        int b   = idx / (KH * 68);
        int rem = idx - b * (KH * 68);
        int r   = rem / 68;
        int c   = rem - r * 68;
        int col = l0 + c;
        col = col > WW - 1 ? WW - 1 : col;     // clamp only feeds invalid lanes
        xs[b][r][c] = x[(b * HH + k + r) * WW + col];
    }
    if (t < NO) {
        float s = 0.f;
        #pragma unroll
        for (int i = 0; i < 25; ++i) { float v = w[t * 25 + i]; s = fmaf(v, v, s); }
        wn[t] = s;
    }
    __syncthreads();

    const int lane = t & 63;
    const int bg   = __builtin_amdgcn_readfirstlane(t >> 6);
    const int l    = l0 + lane;

    float s1 = 0.f, s2 = 0.f;
    #pragma unroll 1
    for (int bi = 0; bi < 2; ++bi) {
        const int b = bg + 8 * bi;
        float pr[25];
        float pn = 0.f;
        #pragma unroll
        for (int r = 0; r < KH; ++r)
            #pragma unroll
            for (int c = 0; c < KW; ++c) {
                float v = xs[b][r][lane + c];
                pr[r * KW + c] = v;
                pn = fmaf(v, v, pn);
            }
        if (l < WO) pnb[b * PLANE + k * WO + l] = pn;   // 4 MB table for pass 2

        v2f prv[12];
        #pragma unroll
        for (int i = 0; i < 12; ++i) { prv[i].x = pr[2 * i]; prv[i].y = pr[2 * i + 1]; }
        const float pr24 = pr[24];

        #pragma unroll 8
        for (int j = 0; j < 32; ++j) {
            float cr0, cr1;
            {
                const float* __restrict__ wr = w + (2 * j) * 25;      // uniform -> s_load
                v2f acc = {0.f, 0.f};
                #pragma unroll
                for (int i = 0; i < 12; ++i) {
                    v2f wv_; wv_.x = wr[2 * i]; wv_.y = wr[2 * i + 1];
                    acc = __builtin_elementwise_fma(prv[i], wv_, acc);
                }
                cr0 = acc.x + acc.y + pr24 * wr[24];
            }
            {
                const float* __restrict__ wr = w + (2 * j + 1) * 25;
                v2f acc = {0.f, 0.f};
                #pragma unroll
                for (int i = 0; i < 12; ++i) {
                    v2f wv_; wv_.x = wr[2 * i]; wv_.y = wr[2 * i + 1];
                    acc = __builtin_elementwise_fma(prv[i], wv_, acc);
                }
                cr1 = acc.x + acc.y + pr24 * wr[24];
            }
            v2f wn2 = *(const v2f*)&wn[2 * j];
            float d20 = fmaxf(fmaf(-2.f, cr0, pn + wn2.x), 1e-12f);
            float d21 = fmaxf(fmaf(-2.f, cr1, pn + wn2.y), 1e-12f);
            s2 += d20 + d21;
            s1 += __builtin_amdgcn_sqrtf(d20) + __builtin_amdgcn_sqrtf(d21);
        }
    }
    pS1[bg][lane] = s1;
    pS2[bg][lane] = s2;
    __syncthreads();

    if (t < T1W) {
        float S1 = 0.f, S2 = 0.f;
        #pragma unroll
        for (int q = 0; q < 8; ++q) { S1 += pS1[q][t]; S2 += pS2[q][t]; }
        const float var = (S2 - S1 * S1 * (1.0f / 1024.0f)) * (1.0f / 1023.0f);
        const int ll = l0 + t;
        if (ll < WO) cinvb[k * WO + ll] = -0.72134752044448170368f / var;
    }
}

// ================= pass 2: contiguous-per-instruction nt stores =================
// Grid (6, 64, 16): block = one (b,o) plane x 42-row chunk. NEW vs r5: thread
// ct owns cols [4ct,4ct+4) and [128+4ct,128+4ct+4), so each v4f store
// instruction is a contiguous 512B run per 32-lane half (no 16B-on/16B-off
// interleave), issued nontemporal (streaming, no L2 allocate).
#define RCH 42
#define XR  46
#define XW  264                       // 256 + 8 zero pad (tail windows)

__global__ __launch_bounds__(512, 4)
void rbf_out_kernel(const float* __restrict__ x, const float* __restrict__ w,
                    const float* __restrict__ cinvb, const float* __restrict__ pnb,
                    float* __restrict__ out) {
    __shared__ float xs[XR][XW];      // 48,576 B -> 3 blocks/CU by LDS

    const int t  = threadIdx.x;
    const int k0 = (int)blockIdx.x * RCH;
    const int o  = blockIdx.y;
    const int b  = blockIdx.z;

    for (int idx = t; idx < XR * 64; idx += 512) {
        const int row = idx >> 6, c4 = (idx & 63) << 2;
        *(v4f*)&xs[row][c4] = *(const v4f*)&x[(b * HH + k0 + row) * WW + c4];
    }
    if (t < XR * 2) {                 // zero the 8-col pad
        const int row = t >> 1, c = 256 + ((t & 1) << 2);
        v4f z = {0.f, 0.f, 0.f, 0.f};
        *(v4f*)&xs[row][c] = z;
    }
    const float* __restrict__ wp = w + o * 25;   // uniform -> scalar loads
    float ws[25]; float wnv = 0.f;
    #pragma unroll
    for (int i = 0; i < 25; ++i) { ws[i] = wp[i]; wnv = fmaf(ws[i], ws[i], wnv); }
    __syncthreads();

    const int ct  = t & 31;
    const int rs  = t >> 5;
    const int cA0 = ct << 2;          // cols 4ct..4ct+3
    const int cB0 = 128 + (ct << 2);  // cols 128+4ct..128+4ct+3
    const int obase = (b * NO + o) * PLANE;

    #pragma unroll 1
    for (int it = 0; it < 3; ++it) {
        const int ki = it * 16 + rs;
        if (ki >= RCH) continue;      // exec-masked tail (no barrier inside loop)
        const int gk = k0 + ki;

        float crA[4] = {0.f, 0.f, 0.f, 0.f};
        float crB[4] = {0.f, 0.f, 0.f, 0.f};
        #pragma unroll
        for (int r = 0; r < KH; ++r) {
            const float* rowp = &xs[ki + r][0];
            v4f a0 = *(const v4f*)&rowp[cA0];
            v4f a1 = *(const v4f*)&rowp[cA0 + 4];
            v4f b0 = *(const v4f*)&rowp[cB0];
            v4f b1 = *(const v4f*)&rowp[cB0 + 4];
            float va[8] = {a0.x, a0.y, a0.z, a0.w, a1.x, a1.y, a1.z, a1.w};
            float vb[8] = {b0.x, b0.y, b0.z, b0.w, b1.x, b1.y, b1.z, b1.w};
            #pragma unroll
            for (int j = 0; j < 4; ++j)
                #pragma unroll
                for (int c = 0; c < KW; ++c) {
                    const float wc = ws[r * KW + c];
                    crA[j] = fmaf(va[j + c], wc, crA[j]);
                    crB[j] = fmaf(vb[j + c], wc, crB[j]);
                }
        }

        const int px = gk * WO + cA0;
        v4f pA = *(const v4f*)&pnb[b * PLANE + px];
        v4f pB = *(const v4f*)&pnb[b * PLANE + px + 128];
        v4f cA = *(const v4f*)&cinvb[px];
        v4f cB = *(const v4f*)&cinvb[px + 128];

        v4f oA, oB;
        oA.x = exp2f(fmaxf(fmaf(-2.f, crA[0], pA.x + wnv), 1e-12f) * cA.x);
        oA.y = exp2f(fmaxf(fmaf(-2.f, crA[1], pA.y + wnv), 1e-12f) * cA.y);
        oA.z = exp2f(fmaxf(fmaf(-2.f, crA[2], pA.z + wnv), 1e-12f) * cA.z);
        oA.w = exp2f(fmaxf(fmaf(-2.f, crA[3], pA.w + wnv), 1e-12f) * cA.w);
        oB.x = exp2f(fmaxf(fmaf(-2.f, crB[0], pB.x + wnv), 1e-12f) * cB.x);
        oB.y = exp2f(fmaxf(fmaf(-2.f, crB[1], pB.y + wnv), 1e-12f) * cB.y);
        oB.z = exp2f(fmaxf(fmaf(-2.f, crB[2], pB.z + wnv), 1e-12f) * cB.z);
        oB.w = exp2f(fmaxf(fmaf(-2.f, crB[3], pB.w + wnv), 1e-12f) * cB.w);

        // lanes 0-31: one contiguous 512B run per store instruction
        __builtin_nontemporal_store(oA, (v4f*)&out[obase + px]);
        if (ct < 31)                  // cols 252..255 tail masked
            __builtin_nontemporal_store(oB, (v4f*)&out[obase + px + 128]);
    }
}

extern "C" void kernel_launch(void* const* d_in, const int* in_sizes, int n_in,
                              void* d_out, int out_size, void* d_ws, size_t ws_size,
                              hipStream_t stream) {
    const float* x = (const float*)d_in[0];
    const float* w = (const float*)d_in[1];
    float* out  = (float*)d_out;
    float* cinv = (float*)d_ws;
    float* pnb  = (float*)d_ws + CINV_FLOATS;

    dim3 g1(4, HO);
    rbf_stats_kernel<<<g1, 512, 0, stream>>>(x, w, cinv, pnb);
    dim3 g2(6, NO, NB);
    rbf_out_kernel<<<g2, 512, 0, stream>>>(x, w, cinv, pnb, out);
}